// Round 9
// baseline (25693.137 us; speedup 1.0000x reference)
//
#include <hip/hip_runtime.h>
#include <hip/hip_bf16.h>
#include <stdint.h>

#define NCH  256
#define EMB  1024
#define HID  2048
#define SEQL 4096

// ---------------- ws layout (bytes) ----------------
static constexpr size_t EG_OFF   = 0;
static constexpr size_t EG_BYTES = (size_t)NCH * 8192 * 4;          // 8,388,608
static constexpr size_t HS_OFF   = EG_OFF + EG_BYTES;
static constexpr size_t HS_BYTES = (size_t)SEQL * HID * 4;          // 33,554,432
static constexpr size_t HB_OFF   = HS_OFF + HS_BYTES;
static constexpr size_t HB_BYTES = 2 * HID * 8;                     // self-tagged u64
static constexpr size_t CF_OFF   = HB_OFF + HB_BYTES;
static constexpr size_t CF_BYTES = HID * 4;
static constexpr size_t WS_NEED  = CF_OFF + CF_BYTES;

// ---------------------------------------------------------------------------
// Kernel A: Eg[c][cu*32 + gate*8 + jl] = bias_g[j] + sum_e emb[c][e]*Wg[e][j]
// ---------------------------------------------------------------------------
__global__ __launch_bounds__(256) void eg_gemm(
    const float* __restrict__ emb,
    const float* __restrict__ Wf, const float* __restrict__ bf,
    const float* __restrict__ Wi, const float* __restrict__ bi,
    const float* __restrict__ Wo, const float* __restrict__ bo,
    const float* __restrict__ Wc, const float* __restrict__ bc,
    float* __restrict__ Eg)
{
    const int nb  = blockIdx.x & 63;
    const int cb  = blockIdx.x >> 6;
    const int tid = threadIdx.x;
    const int col = tid & 127;
    const int gate = col >> 5;
    const int jj   = col & 31;
    const int j    = nb * 32 + jj;
    const int mh   = tid >> 7;

    __shared__ float embT[32][65];
    __shared__ float Wt[32][128];

    float acc[32];
#pragma unroll
    for (int m = 0; m < 32; ++m) acc[m] = 0.f;

    for (int k0 = 0; k0 < EMB; k0 += 32) {
        __syncthreads();
        for (int i = tid; i < 64 * 32; i += 256) {
            int c = i >> 5, kk = i & 31;
            embT[kk][c] = emb[(size_t)(cb * 64 + c) * EMB + k0 + kk];
        }
        for (int i = tid; i < 32 * 128; i += 256) {
            int kk = i >> 7, cl = i & 127;
            int g2 = cl >> 5;
            int jx = nb * 32 + (cl & 31);
            const float* Wp = (g2 == 0) ? Wf : (g2 == 1) ? Wi : (g2 == 2) ? Wo : Wc;
            Wt[kk][cl] = Wp[(size_t)(k0 + kk) * HID + jx];
        }
        __syncthreads();
#pragma unroll 8
        for (int kk = 0; kk < 32; ++kk) {
            float w = Wt[kk][col];
#pragma unroll
            for (int m = 0; m < 32; ++m)
                acc[m] += embT[kk][mh * 32 + m] * w;
        }
    }
    const float* bias = (gate == 0) ? bf : (gate == 1) ? bi : (gate == 2) ? bo : bc;
    float bv = bias[j];
    for (int m = 0; m < 32; ++m) {
        int c = cb * 64 + mh * 32 + m;
        Eg[(size_t)c * 8192 + (j >> 3) * 32 + gate * 8 + (j & 7)] = acc[m] + bv;
    }
}

// ---------------------------------------------------------------------------
// bulk fetch: two 16B fresh loads, one round trip (R8-proven path; system
// scope is conservative-correct: reads see agent-scope L3 data)
// ---------------------------------------------------------------------------
__device__ inline void bulk2(const void* p0, const void* p1, uint4& a, uint4& b)
{
    asm volatile(
        "global_load_dwordx4 %0, %2, off sc0 sc1\n\t"
        "global_load_dwordx4 %1, %3, off sc0 sc1\n\t"
        "s_waitcnt vmcnt(0)"
        : "=&v"(a), "=&v"(b)
        : "v"(p0), "v"(p1)
        : "memory");
}

// ---------------------------------------------------------------------------
// Kernel B: persistent sequential LSTM, self-tagged single-hop exchange.
// hb2[slot][j] : u64 = (tag=t+1)<<32 | f32bits(h_j).
// R9 changes vs R8:
//  - fast-poll spins on ONE u64 via compiler agent-scope atomic (L3-serviced,
//    guaranteed-correct cache ops; R8's hand-rolled sc0+sc1 polls were
//    system-scope -> HBM round trips, FETCH 1.37 GB); bulk2 only after detect
//  - double-buffered h_lds -> ONE __syncthreads per step
//  - cell state replicated across all 64 lanes (4 shfl broadcasts, no
//    divergent lane-0 exp tail); lane 0 only stores
//  - weights unpinned (R7/R8 "+a" pinning cost ~2x VALU, zero benefit)
// ---------------------------------------------------------------------------
#define REP32(M) M(0) M(1) M(2) M(3) M(4) M(5) M(6) M(7) M(8) M(9) M(10) M(11) \
  M(12) M(13) M(14) M(15) M(16) M(17) M(18) M(19) M(20) M(21) M(22) M(23)      \
  M(24) M(25) M(26) M(27) M(28) M(29) M(30) M(31)

__global__ __launch_bounds__(512, 2) void lstm_seq(
    const int*   __restrict__ seq,
    const float* __restrict__ h0,
    const float* __restrict__ c0,
    const float* __restrict__ Wf, const float* __restrict__ Wi,
    const float* __restrict__ Wo, const float* __restrict__ Wc,
    const float* __restrict__ Eg,
    float* __restrict__ Hs,
    unsigned long long* hb2, float* cfin)
{
    const int cu   = blockIdx.x;      // 0..255
    const int tid  = threadIdx.x;     // 0..511
    const int lane = tid & 63;
    const int wave = tid >> 6;        // 0..7
    const int g    = lane >> 4;       // gate 0..3 (f,i,o,c)
    const int kp   = lane & 15;       // k-interleave slot
    const int jcol = cu * 8 + wave;   // this wave's output column

    const float* W = (g == 0) ? Wf : (g == 1) ? Wi : (g == 2) ? Wo : Wc;

    // ---- 128 recurrent weights in named registers ----
    // row(i,q) = 1024 + (i*16+kp)*4 + q  -> offset from Wb: (i*64+q)*HID
    const float* Wb = W + (size_t)(1024 + kp * 4) * HID + jcol;
#define WDECL(i) float4 w##i;
    REP32(WDECL)
#undef WDECL
#define WLOAD(i) { w##i.x = Wb[(size_t)((i)*64+0)*HID]; \
                   w##i.y = Wb[(size_t)((i)*64+1)*HID]; \
                   w##i.z = Wb[(size_t)((i)*64+2)*HID]; \
                   w##i.w = Wb[(size_t)((i)*64+3)*HID]; }
    REP32(WLOAD)
#undef WLOAD

    __shared__ __align__(16) float h_lds[2][HID];   // double buffer: 16 KB
    __shared__ int seq_lds[SEQL];                   // 16 KB

    for (int i = tid; i < SEQL; i += 512) seq_lds[i] = seq[i];
    for (int i = tid; i < HID;  i += 512) h_lds[0][i] = h0[i];
    float c = c0[jcol];               // replicated across all lanes (broadcast)
    __syncthreads();

    for (int t = 0; t < SEQL; ++t) {
        // ---- Eg for this wave's column (issued early, off critical path) ----
        float egv = Eg[(size_t)seq_lds[t] * 8192 + cu * 32 + g * 8 + wave];

        // ---- matvec: 128 MACs/lane from registers, h from LDS buffer t&1 ----
        const float4* hp = (const float4*)(h_lds[t & 1]);
        float accv[4] = {0.f, 0.f, 0.f, 0.f};
#define WMAC(i) { float4 hv = hp[(i)*16 + kp]; \
                  accv[(i)&3] += w##i.x*hv.x + w##i.y*hv.y + w##i.z*hv.z + w##i.w*hv.w; }
        REP32(WMAC)
#undef WMAC
        float sum = (accv[0] + accv[1]) + (accv[2] + accv[3]);

        // ---- intra-wave reduce over the 16 k-slots ----
        sum += __shfl_xor(sum, 1, 16);
        sum += __shfl_xor(sum, 2, 16);
        sum += __shfl_xor(sum, 4, 16);
        sum += __shfl_xor(sum, 8, 16);

        // ---- activation per gate group ----
        float pre = sum + egv;
        float act;
        if (g < 3) {
            act = 1.f / (1.f + __expf(-pre));
        } else {
            float e = __expf(2.f * pre);
            act = 1.f - 2.f / (e + 1.f);
        }
        // broadcast all four gate values to every lane
        float f_ = __shfl(act, 0,  64);
        float i_ = __shfl(act, 16, 64);
        float o_ = __shfl(act, 32, 64);
        float g_ = __shfl(act, 48, 64);

        // ---- cell update, replicated on all lanes (no serial tail) ----
        c = f_ * c + i_ * g_;
        float e2 = __expf(2.f * c);
        float hn = o_ * (1.f - 2.f / (e2 + 1.f));

        if (lane == 0) {
            Hs[(size_t)t * HID + jcol] = hn;
            unsigned long long pk =
                ((unsigned long long)(unsigned)(t + 1) << 32) |
                (unsigned long long)__float_as_uint(hn);
            __hip_atomic_store(&hb2[(size_t)((t + 1) & 1) * HID + jcol], pk,
                               __ATOMIC_RELAXED, __HIP_MEMORY_SCOPE_AGENT);
        }

        // ---- poll + stage h(t+1): thread covers j = 4*tid .. 4*tid+3 ----
        if (t + 1 < SEQL) {
            const unsigned tgt = (unsigned)(t + 1);
            unsigned long long* sl = hb2 + (size_t)((t + 1) & 1) * HID;
            unsigned long long* mp = sl + 4 * tid;

            // fast-poll on first u64: agent-scope (L3), compiler-correct bits
            if ((unsigned)(__hip_atomic_load(mp, __ATOMIC_RELAXED,
                                             __HIP_MEMORY_SCOPE_AGENT) >> 32) < tgt) {
                do {
                    __builtin_amdgcn_s_sleep(1);
                } while ((unsigned)(__hip_atomic_load(mp, __ATOMIC_RELAXED,
                                                      __HIP_MEMORY_SCOPE_AGENT) >> 32) < tgt);
            }

            // bulk fetch all 4 slots; re-loop until all tags current
            uint4 a, b;
            bulk2(mp, mp + 2, a, b);
            while (a.y < tgt || a.w < tgt || b.y < tgt || b.w < tgt) {
                __builtin_amdgcn_s_sleep(1);
                bulk2(mp, mp + 2, a, b);
            }

            float4 hv;
            hv.x = __uint_as_float(a.x);
            hv.y = __uint_as_float(a.z);
            hv.z = __uint_as_float(b.x);
            hv.w = __uint_as_float(b.z);
            ((float4*)h_lds[(t + 1) & 1])[tid] = hv;
            __syncthreads();            // single barrier per step
        }
    }

    if (lane == 0) cfin[jcol] = c;
}

// ---------------------------------------------------------------------------
// Kernel C: preds = Hs @ Wy + by
// ---------------------------------------------------------------------------
__global__ __launch_bounds__(256) void y_gemm(
    const float* __restrict__ Hs, const float* __restrict__ Wy,
    const float* __restrict__ by, float* __restrict__ out)
{
    const int rb  = blockIdx.x * 16;
    const int tid = threadIdx.x;
    __shared__ float A[16][68];
    float acc[16];
#pragma unroll
    for (int r = 0; r < 16; ++r) acc[r] = 0.f;

    for (int k0 = 0; k0 < HID; k0 += 64) {
        __syncthreads();
        for (int i = tid; i < 16 * 64; i += 256) {
            int r = i >> 6, kk = i & 63;
            A[r][kk] = Hs[(size_t)(rb + r) * HID + k0 + kk];
        }
        __syncthreads();
#pragma unroll 8
        for (int kk = 0; kk < 64; ++kk) {
            float b = Wy[(size_t)(k0 + kk) * NCH + tid];
#pragma unroll
            for (int r = 0; r < 16; ++r) acc[r] += A[r][kk] * b;
        }
    }
    float bv = by[tid];
    for (int r = 0; r < 16; ++r)
        out[(size_t)(rb + r) * NCH + tid] = acc[r] + bv;
}

// ---------------------------------------------------------------------------
__global__ void fin_copy(const float* __restrict__ Hs,
                         const float* __restrict__ cfin,
                         float* __restrict__ out)
{
    int i = blockIdx.x * 256 + threadIdx.x;
    if (i < HID)
        out[(size_t)SEQL * NCH + i] = Hs[(size_t)(SEQL - 1) * HID + i];
    else
        out[(size_t)SEQL * NCH + i] = cfin[i - HID];
}

// ---------------------------------------------------------------------------
extern "C" void kernel_launch(void* const* d_in, const int* in_sizes, int n_in,
                              void* d_out, int out_size, void* d_ws, size_t ws_size,
                              hipStream_t stream)
{
    if (n_in < 14 || ws_size < WS_NEED) return;

    const int*   seq = (const int*)  d_in[0];
    const float* h0  = (const float*)d_in[1];
    const float* c0  = (const float*)d_in[2];
    const float* emb = (const float*)d_in[3];
    const float* Wf  = (const float*)d_in[4];
    const float* bf  = (const float*)d_in[5];
    const float* Wi  = (const float*)d_in[6];
    const float* bi  = (const float*)d_in[7];
    const float* Wo  = (const float*)d_in[8];
    const float* bo  = (const float*)d_in[9];
    const float* Wc  = (const float*)d_in[10];
    const float* bc  = (const float*)d_in[11];
    const float* Wy  = (const float*)d_in[12];
    const float* by  = (const float*)d_in[13];

    char* ws = (char*)d_ws;
    float*              Eg   = (float*)(ws + EG_OFF);
    float*              Hs   = (float*)(ws + HS_OFF);
    unsigned long long* hb2  = (unsigned long long*)(ws + HB_OFF);
    float*              cfin = (float*)(ws + CF_OFF);
    float*              out  = (float*)d_out;

    // clear self-tagged exchange buffer every call (poison/stale tags)
    hipMemsetAsync(hb2, 0, HB_BYTES, stream);

    eg_gemm<<<256, 256, 0, stream>>>(emb, Wf, bf, Wi, bi, Wo, bo, Wc, bc, Eg);

    lstm_seq<<<256, 512, 0, stream>>>(seq, h0, c0, Wf, Wi, Wo, Wc, Eg,
                                      Hs, hb2, cfin);

    y_gemm<<<256, 256, 0, stream>>>(Hs, Wy, by, out);

    fin_copy<<<16, 256, 0, stream>>>(Hs, cfin, out);
}